// Round 21
// baseline (343.857 us; speedup 1.0000x reference)
//
#include <hip/hip_runtime.h>
#include <stdint.h>

// ---- dims ----
// B=8, L=27, T=256, D=1152, GS=3, G=9, DD=512, H=8, HD=64, NQ=1, OD=2048
// Output dtype: FLOAT32 (verified round 4).
//
// Round 21: re-fuse score+softmax+VA into ONE per-bl kernel (216 x 1024),
// using the r20-proven internals (transposed-LDS score body, butterfly
// softmax, broadcast-attn VA). Removes the global score->va barrier, the
// scores ws round trip, and one launch ramp. 4 launches total.
// Algebra (verified r9-r20): scores = K·Qk (bk cancels in softmax);
// pooled = (attn·V)·Wv + bv. All f32.

// ---------------------------------------------------------------------------
// K1: qk_fused. grid (27,8,3) = (l,h,dc), block 256.  [verbatim r18-r20]
// ---------------------------------------------------------------------------
__global__ __launch_bounds__(256) void qk_fused(
    const float* __restrict__ query, const float* __restrict__ Wq,
    const float* __restrict__ bq, const float* __restrict__ Wk,
    float* __restrict__ Qk)
{
  const int l = blockIdx.x, g = l / 3;
  const int h = blockIdx.y;
  const int dc = blockIdx.z;          // 0..2 (384 d each)
  const int tid = threadIdx.x;

  __shared__ float qv[1152];
  __shared__ float part[4][64];
  __shared__ float Qps[64];

  for (int i = tid; i < 1152; i += 256) qv[i] = query[(size_t)l * 1152 + i];
  __syncthreads();

  {
    const int e = tid & 63;
    const int kq = tid >> 6;          // 0..3, 288 d' each
    const float* W = Wq + (size_t)g * 1152 * 512 + h * 64 + e;
    float a0 = 0.f, a1 = 0.f;
    const int d0 = kq * 288;
#pragma unroll 4
    for (int d = d0; d < d0 + 288; d += 2) {
      a0 += qv[d]     * W[(size_t)d * 512];
      a1 += qv[d + 1] * W[(size_t)(d + 1) * 512];
    }
    part[kq][e] = a0 + a1;
  }
  __syncthreads();
  if (tid < 64) {
    const float r = part[0][tid] + part[1][tid] + part[2][tid] + part[3][tid];
    Qps[tid] = (r + bq[g * 512 + h * 64 + tid]) * 0.125f;
  }
  __syncthreads();

  const float4* q4base = (const float4*)Qps;
#pragma unroll
  for (int it = 0; it < 6; it++) {
    const int slot = it * 256 + tid;  // 0..1535
    const int eg = slot & 3;
    const int d  = dc * 384 + (slot >> 2);
    const float4* q4 = q4base + eg * 4;
    const float4* w4 = (const float4*)(Wk + (size_t)g * 1152 * 512 + (size_t)d * 512 + h * 64 + eg * 16);
    float acc = 0.f;
#pragma unroll
    for (int e = 0; e < 4; e++) {
      const float4 a = q4[e], b = w4[e];
      acc += a.x * b.x + a.y * b.y + a.z * b.z + a.w * b.w;
    }
    acc += __shfl_xor(acc, 1, 64);
    acc += __shfl_xor(acc, 2, 64);
    if (eg == 0) Qk[((size_t)l * 1152 + d) * 8 + h] = acc;
  }
}

// ---------------------------------------------------------------------------
// K2: attn_fused — scores + softmax + VA per bl.  grid 216, block 1024.
// Score: 4 token-tiles serially; per tile 6 chunks of 192 d; K staged
// transposed Kt[d][t] stride 65 (conflict-free), Qk chunk broadcast from
// Qs; wave = 12-d slice; depth-1 register prefetch; 16-way LDS reduce
// into sm[256][8]. Softmax: r20 butterfly (threads<256). VA: d = tid
// (+1024 extras on tid<128), unroll 8, broadcast attn reads.
// ---------------------------------------------------------------------------
__global__ __launch_bounds__(1024) void attn_fused(
    const float* __restrict__ K, const float* __restrict__ V,
    const float* __restrict__ Qk, float* __restrict__ VA)
{
  const int bl = blockIdx.x;          // 0..215
  const int l = bl % 27;
  const int tid = threadIdx.x;
  const int lane = tid & 63;
  const int wid = tid >> 6;           // 0..15

  __shared__ __align__(16) float Kt[192 * 65];   // 49,920 B; overlaid red16
  __shared__ __align__(16) float Qs[192 * 8];    // 6,144 B
  __shared__ __align__(16) float sm[256 * 8];    // 8 KB: scores -> attn
  __shared__ float red[4][8], red2[4][8];

  const float* Qbase = Qk + (size_t)l * 1152 * 8;

  // ======== score phase ========
  for (int tq = 0; tq < 4; tq++) {
    const float* Kbase = K + ((size_t)bl * 256 + tq * 64) * 1152;
    float sc[8] = {0.f, 0.f, 0.f, 0.f, 0.f, 0.f, 0.f, 0.f};

    float4 kreg[3]; float4 qreg;
    // prefetch chunk 0
#pragma unroll
    for (int it = 0; it < 3; it++) {
      const int flat = it * 1024 + tid;        // float4 slot (3072 total)
      const int row = flat / 48, col = flat % 48;
      kreg[it] = *(const float4*)(Kbase + (size_t)row * 1152 + col * 4);
    }
    if (tid < 384) qreg = ((const float4*)Qbase)[tid];

    for (int dc = 0; dc < 6; dc++) {
      // store staged chunk -> LDS (transposed)
#pragma unroll
      for (int it = 0; it < 3; it++) {
        const int flat = it * 1024 + tid;
        const int row = flat / 48, col = flat % 48;
        Kt[(col * 4 + 0) * 65 + row] = kreg[it].x;
        Kt[(col * 4 + 1) * 65 + row] = kreg[it].y;
        Kt[(col * 4 + 2) * 65 + row] = kreg[it].z;
        Kt[(col * 4 + 3) * 65 + row] = kreg[it].w;
      }
      if (tid < 384) ((float4*)Qs)[tid] = qreg;
      __syncthreads();
      // prefetch chunk dc+1 (flies over compute)
      if (dc + 1 < 6) {
#pragma unroll
        for (int it = 0; it < 3; it++) {
          const int flat = it * 1024 + tid;
          const int row = flat / 48, col = flat % 48;
          kreg[it] = *(const float4*)(Kbase + (size_t)row * 1152 + (dc + 1) * 192 + col * 4);
        }
        if (tid < 384) qreg = ((const float4*)(Qbase + (size_t)(dc + 1) * 192 * 8))[tid];
      }
      // compute: wave wid handles d in [wid*12, wid*12+12)
#pragma unroll 4
      for (int j = 0; j < 12; j++) {
        const int d = wid * 12 + j;
        const float kv = Kt[d * 65 + lane];            // bank=(d+lane)%32: free
        const float4 qa = *(const float4*)&Qs[d * 8];  // broadcast
        const float4 qb = *(const float4*)&Qs[d * 8 + 4];
        sc[0] = fmaf(kv, qa.x, sc[0]); sc[1] = fmaf(kv, qa.y, sc[1]);
        sc[2] = fmaf(kv, qa.z, sc[2]); sc[3] = fmaf(kv, qa.w, sc[3]);
        sc[4] = fmaf(kv, qb.x, sc[4]); sc[5] = fmaf(kv, qb.y, sc[5]);
        sc[6] = fmaf(kv, qb.z, sc[6]); sc[7] = fmaf(kv, qb.w, sc[7]);
      }
      __syncthreads();
    }

    // 16-way reduce per (t,h) via Kt overlay: red16[w][t][h]
    *(float4*)&Kt[(wid * 64 + lane) * 8    ] = make_float4(sc[0], sc[1], sc[2], sc[3]);
    *(float4*)&Kt[(wid * 64 + lane) * 8 + 4] = make_float4(sc[4], sc[5], sc[6], sc[7]);
    __syncthreads();
    if (tid < 512) {
      const int t = tid >> 3, h = tid & 7;
      float s = 0.f;
#pragma unroll
      for (int w = 0; w < 16; w++) s += Kt[(w * 64 + t) * 8 + h];
      sm[(tq * 64 + t) * 8 + h] = s;
    }
    __syncthreads();   // before next tq overwrites Kt
  }

  // ======== softmax (threads < 256, r20 butterfly) ========
  float p[8], scl[8];
  if (tid < 256) {
#pragma unroll
    for (int h = 0; h < 8; h++) scl[h] = sm[tid * 8 + h];
#pragma unroll
    for (int h = 0; h < 8; h++) {
      float m = scl[h];
#pragma unroll
      for (int o = 1; o < 64; o <<= 1) m = fmaxf(m, __shfl_xor(m, o, 64));
      if (lane == 0) red[wid][h] = m;
    }
  }
  __syncthreads();
  if (tid < 256) {
#pragma unroll
    for (int h = 0; h < 8; h++) {
      const float M = fmaxf(fmaxf(red[0][h], red[1][h]), fmaxf(red[2][h], red[3][h]));
      p[h] = __expf(scl[h] - M);
      float s = p[h];
#pragma unroll
      for (int o = 1; o < 64; o <<= 1) s += __shfl_xor(s, o, 64);
      if (lane == 0) red2[wid][h] = s;
    }
  }
  __syncthreads();
  if (tid < 256) {
#pragma unroll
    for (int h = 0; h < 8; h++) {
      const float S = red2[0][h] + red2[1][h] + red2[2][h] + red2[3][h];
      sm[tid * 8 + h] = p[h] * (1.0f / S);     // attn, in-place
    }
  }
  __syncthreads();

  // ======== VA phase ========
  const float* Vbl = V + (size_t)bl * 256 * 1152;
  const int d  = tid;                  // 0..1023
  const int d2 = 1024 + tid;           // valid for tid < 128
  const bool has2 = (tid < 128);
  float acc[8]  = {0.f, 0.f, 0.f, 0.f, 0.f, 0.f, 0.f, 0.f};
  float acc2[8] = {0.f, 0.f, 0.f, 0.f, 0.f, 0.f, 0.f, 0.f};
#pragma unroll 8
  for (int t = 0; t < 256; t++) {
    const float v = Vbl[(size_t)t * 1152 + d];
    const float4 a0 = *(const float4*)&sm[t * 8];      // broadcast
    const float4 a1 = *(const float4*)&sm[t * 8 + 4];  // broadcast
    acc[0] = fmaf(a0.x, v, acc[0]); acc[1] = fmaf(a0.y, v, acc[1]);
    acc[2] = fmaf(a0.z, v, acc[2]); acc[3] = fmaf(a0.w, v, acc[3]);
    acc[4] = fmaf(a1.x, v, acc[4]); acc[5] = fmaf(a1.y, v, acc[5]);
    acc[6] = fmaf(a1.z, v, acc[6]); acc[7] = fmaf(a1.w, v, acc[7]);
    if (has2) {
      const float w = Vbl[(size_t)t * 1152 + d2];
      acc2[0] = fmaf(a0.x, w, acc2[0]); acc2[1] = fmaf(a0.y, w, acc2[1]);
      acc2[2] = fmaf(a0.z, w, acc2[2]); acc2[3] = fmaf(a0.w, w, acc2[3]);
      acc2[4] = fmaf(a1.x, w, acc2[4]); acc2[5] = fmaf(a1.y, w, acc2[5]);
      acc2[6] = fmaf(a1.z, w, acc2[6]); acc2[7] = fmaf(a1.w, w, acc2[7]);
    }
  }
  float* dst = VA + (size_t)bl * 8 * 1152;
#pragma unroll
  for (int h = 0; h < 8; h++) {
    dst[(size_t)h * 1152 + d] = acc[h];
    if (has2) dst[(size_t)h * 1152 + d2] = acc2[h];
  }
}

// ---------------------------------------------------------------------------
// K3: psum[dz][bl][e*8+h] = sum_{d in quarter dz} VA[bl,h,d]*Wv[g,d,h*64+e]
// grid (27,8,4) = (l,h,dz); block 512.  [verbatim r19/r20]
// ---------------------------------------------------------------------------
__global__ __launch_bounds__(512) void pv_mat(
    const float* __restrict__ VA, const float* __restrict__ Wv,
    float* __restrict__ psum)
{
  const int l = blockIdx.x, g = l / 3, h = blockIdx.y, dz = blockIdx.z;
  const int b = threadIdx.x >> 6, lane = threadIdx.x & 63;
  const int bl = b * 27 + l;
  const float* W = Wv + (size_t)g * 1152 * 512 + h * 64 + lane;
  const float* va = VA + ((size_t)bl * 8 + h) * 1152;   // wave-uniform
  const int d0 = dz * 288;
  float a0 = 0.f, a1 = 0.f, a2 = 0.f, a3 = 0.f;
#pragma unroll 2
  for (int d = d0; d < d0 + 288; d += 4) {
    a0 = fmaf(va[d],     W[(size_t)(d)     * 512], a0);
    a1 = fmaf(va[d + 1], W[(size_t)(d + 1) * 512], a1);
    a2 = fmaf(va[d + 2], W[(size_t)(d + 2) * 512], a2);
    a3 = fmaf(va[d + 3], W[(size_t)(d + 3) * 512], a3);
  }
  psum[((size_t)dz * 216 + bl) * 512 + lane * 8 + h] = (a0 + a1) + (a2 + a3);
}

// ---------------------------------------------------------------------------
// K4: out[bl,n] = pooled[bl,:]@Wo[g] + bo[g];  pooled = sum_dz psum + bv_perm
// grid (27,8), block 256.  [verbatim r19/r20]
// ---------------------------------------------------------------------------
__global__ __launch_bounds__(256) void out_gemm(
    const float* __restrict__ psum, const float* __restrict__ bv,
    const float* __restrict__ Wo, const float* __restrict__ bo,
    float* __restrict__ out)
{
  const int l = blockIdx.x, g = l / 3;
  const int n = blockIdx.y * 256 + threadIdx.x;
  __shared__ float pl[8][512];
  for (int i = threadIdx.x; i < 4096; i += 256) {
    const int b = i >> 9, f = i & 511;
    const int bl = b * 27 + l;
    const int e = f >> 3, h = f & 7;           // f = e*8 + h
    float v = bv[g * 512 + h * 64 + e];
#pragma unroll
    for (int dz = 0; dz < 4; dz++)
      v += psum[((size_t)dz * 216 + bl) * 512 + f];
    pl[b][f] = v;
  }
  __syncthreads();
  const float* W = Wo + (size_t)g * 512 * 2048 + n;
  float acc[8] = {0.f, 0.f, 0.f, 0.f, 0.f, 0.f, 0.f, 0.f};
#pragma unroll 4
  for (int f = 0; f < 512; f++) {
    const float w = W[(size_t)f * 2048];
#pragma unroll
    for (int b = 0; b < 8; b++) acc[b] += pl[b][f] * w;
  }
  const float bb = bo[g * 2048 + n];
#pragma unroll
  for (int b = 0; b < 8; b++)
    out[(size_t)(b * 27 + l) * 2048 + n] = acc[b] + bb;
}

// ---------------------------------------------------------------------------
// sentinel: zero-fill f32 output (absmax would read ~1.06e-1 = max|ref|)
// ---------------------------------------------------------------------------
__global__ __launch_bounds__(256) void zfill(float* __restrict__ out, int n) {
  const int i = blockIdx.x * 256 + threadIdx.x;
  if (i < n) out[i] = 0.f;
}

// ---------------------------------------------------------------------------
extern "C" void kernel_launch(void* const* d_in, const int* in_sizes, int n_in,
                              void* d_out, int out_size, void* d_ws, size_t ws_size,
                              hipStream_t stream)
{
  float* out = (float*)d_out;   // f32 output (verified round 4)

  // ---- config guards ----
  bool ok = (n_in == 11) && (out_size == 8 * 27 * 2048);
  if (ok) {
    const int expect[11] = {
      8 * 27 * 256 * 1152,  // K
      8 * 27 * 256 * 1152,  // V
      27 * 1 * 1152,        // query
      9 * 1152 * 512,       // Wq
      9 * 512,              // bq
      9 * 1152 * 512,       // Wk
      9 * 512,              // bk
      9 * 1152 * 512,       // Wv
      9 * 512,              // bv
      9 * 512 * 2048,       // Wo
      9 * 2048              // bo
    };
    for (int i = 0; i < 11; i++) ok = ok && (in_sizes[i] == expect[i]);
  }
  const size_t NEED = 14321664;
  ok = ok && (ws_size >= NEED);

  if (!ok) {
    zfill<<<dim3((out_size + 255) / 256), dim3(256), 0, stream>>>(out, out_size);
    return;
  }

  const float* Kin   = (const float*)d_in[0];
  const float* Vin   = (const float*)d_in[1];
  const float* query = (const float*)d_in[2];
  const float* Wq    = (const float*)d_in[3];
  const float* bq    = (const float*)d_in[4];
  const float* Wk    = (const float*)d_in[5];
  const float* Wv    = (const float*)d_in[7];
  const float* bvp   = (const float*)d_in[8];
  const float* Wo    = (const float*)d_in[9];
  const float* bo    = (const float*)d_in[10];
  // bk (d_in[6]) unused: constant over t, cancels in softmax exactly.

  char* ws = (char*)d_ws;
  float* Qkw   = (float*)(ws + 55296);
  float* VAw   = (float*)(ws + 4589568);
  float* psumw = (float*)(ws + 12552192);

  qk_fused  <<<dim3(27, 8, 3), dim3(256),  0, stream>>>(query, Wq, bq, Wk, Qkw);
  attn_fused<<<dim3(216),      dim3(1024), 0, stream>>>(Kin, Vin, Qkw, VAw);
  pv_mat    <<<dim3(27, 8, 4), dim3(512),  0, stream>>>(VAw, Wv, psumw);
  out_gemm  <<<dim3(27, 8),    dim3(256),  0, stream>>>(psumw, bvp, Wo, bo, out);
}

// Round 22
// 263.780 us; speedup vs baseline: 1.3036x; 1.3036x over previous
//
#include <hip/hip_runtime.h>
#include <stdint.h>

// ---- dims ----
// B=8, L=27, T=256, D=1152, GS=3, G=9, DD=512, H=8, HD=64, NQ=1, OD=2048
// Output dtype: FLOAT32 (verified round 4).
//
// Round 22: REVERT to the round-19 configuration (best measured: 262.2us).
// r20 (depth-2 prefetch + grid swaps) = +3.2us (noise); r21 (mega-fusion)
// = +81us (0.84 blocks/CU starved the barriers). This is the r19 source
// byte-for-byte.
// Algebra (verified r9-r21): scores = K·Qk (bk cancels in softmax);
// pooled = (attn·V)·Wv + bv. All f32.

// ---------------------------------------------------------------------------
// K1: qk_fused. grid (27,8,3) = (l,h,dc), block 256.
// ---------------------------------------------------------------------------
__global__ __launch_bounds__(256) void qk_fused(
    const float* __restrict__ query, const float* __restrict__ Wq,
    const float* __restrict__ bq, const float* __restrict__ Wk,
    float* __restrict__ Qk)
{
  const int l = blockIdx.x, g = l / 3;
  const int h = blockIdx.y;
  const int dc = blockIdx.z;          // 0..2 (384 d each)
  const int tid = threadIdx.x;

  __shared__ float qv[1152];
  __shared__ float part[4][64];
  __shared__ float Qps[64];

  for (int i = tid; i < 1152; i += 256) qv[i] = query[(size_t)l * 1152 + i];
  __syncthreads();

  {
    const int e = tid & 63;
    const int kq = tid >> 6;          // 0..3, 288 d' each
    const float* W = Wq + (size_t)g * 1152 * 512 + h * 64 + e;
    float a0 = 0.f, a1 = 0.f;
    const int d0 = kq * 288;
#pragma unroll 4
    for (int d = d0; d < d0 + 288; d += 2) {
      a0 += qv[d]     * W[(size_t)d * 512];
      a1 += qv[d + 1] * W[(size_t)(d + 1) * 512];
    }
    part[kq][e] = a0 + a1;
  }
  __syncthreads();
  if (tid < 64) {
    const float r = part[0][tid] + part[1][tid] + part[2][tid] + part[3][tid];
    Qps[tid] = (r + bq[g * 512 + h * 64 + tid]) * 0.125f;
  }
  __syncthreads();

  const float4* q4base = (const float4*)Qps;
#pragma unroll
  for (int it = 0; it < 6; it++) {
    const int slot = it * 256 + tid;  // 0..1535
    const int eg = slot & 3;
    const int d  = dc * 384 + (slot >> 2);
    const float4* q4 = q4base + eg * 4;
    const float4* w4 = (const float4*)(Wk + (size_t)g * 1152 * 512 + (size_t)d * 512 + h * 64 + eg * 16);
    float acc = 0.f;
#pragma unroll
    for (int e = 0; e < 4; e++) {
      const float4 a = q4[e], b = w4[e];
      acc += a.x * b.x + a.y * b.y + a.z * b.z + a.w * b.w;
    }
    acc += __shfl_xor(acc, 1, 64);
    acc += __shfl_xor(acc, 2, 64);
    if (eg == 0) Qk[((size_t)l * 1152 + d) * 8 + h] = acc;
  }
}

// ---------------------------------------------------------------------------
// K2: scores[bl][t][h] = sum_d K[bl,t,d] * Qk[l,d,h]
// grid (216,4 token-tiles), block 256 (4 waves). lane = token, wave = d-slice.
// r17 transposed-LDS structure + T14 async-STAGE: prefetch chunk dc+1 into
// regs (6x float4 K + 1 float4 Qs) during compute of chunk dc.
// ---------------------------------------------------------------------------
__global__ __launch_bounds__(256) void score_k(
    const float* __restrict__ K, const float* __restrict__ Qk,
    float* __restrict__ scores)
{
  const int bl = blockIdx.x;          // 0..215
  const int tq = blockIdx.y;          // 0..3 (64-token tile)
  const int l = bl % 27;
  const int tid = threadIdx.x;
  const int lane = tid & 63;          // token within tile
  const int wid = tid >> 6;           // wave = d-slice (24 d of each 96)

  __shared__ __align__(16) float Kt[96 * 65];   // 24,960 B; reused for reduce
  __shared__ __align__(16) float Qs[96 * 8];    // 3,072 B

  const float* Kbase = K + ((size_t)bl * 256 + tq * 64) * 1152;
  const float* Qbase = Qk + (size_t)l * 1152 * 8;

  float4 kreg[6];
  float4 qreg;

  auto loadChunk = [&](int dc) {
#pragma unroll
    for (int it = 0; it < 6; it++) {
      const int flat = it * 256 + tid;       // float4 slot
      const int row = flat / 24;             // token
      const int col = flat % 24;             // d4-slot
      kreg[it] = *(const float4*)(Kbase + (size_t)row * 1152 + dc * 96 + col * 4);
    }
    if (tid < 192)
      qreg = ((const float4*)(Qbase + (size_t)dc * 96 * 8))[tid];
  };
  auto storeChunk = [&]() {
#pragma unroll
    for (int it = 0; it < 6; it++) {
      const int flat = it * 256 + tid;
      const int row = flat / 24;
      const int col = flat % 24;
      Kt[(col * 4 + 0) * 65 + row] = kreg[it].x;
      Kt[(col * 4 + 1) * 65 + row] = kreg[it].y;
      Kt[(col * 4 + 2) * 65 + row] = kreg[it].z;
      Kt[(col * 4 + 3) * 65 + row] = kreg[it].w;
    }
    if (tid < 192)
      ((float4*)Qs)[tid] = qreg;
  };

  float sc[8] = {0.f, 0.f, 0.f, 0.f, 0.f, 0.f, 0.f, 0.f};

  loadChunk(0);
  for (int dc = 0; dc < 12; dc++) {
    storeChunk();
    __syncthreads();
    if (dc + 1 < 12) loadChunk(dc + 1);   // loads fly over compute
    // compute: wave wid handles d in [wid*24, wid*24+24)
#pragma unroll 4
    for (int j = 0; j < 24; j++) {
      const int d = wid * 24 + j;
      const float kv = Kt[d * 65 + lane];            // bank=(d+lane)%32: free
      const float4 qa = *(const float4*)&Qs[d * 8];  // wave-uniform broadcast
      const float4 qb = *(const float4*)&Qs[d * 8 + 4];
      sc[0] = fmaf(kv, qa.x, sc[0]); sc[1] = fmaf(kv, qa.y, sc[1]);
      sc[2] = fmaf(kv, qa.z, sc[2]); sc[3] = fmaf(kv, qa.w, sc[3]);
      sc[4] = fmaf(kv, qb.x, sc[4]); sc[5] = fmaf(kv, qb.y, sc[5]);
      sc[6] = fmaf(kv, qb.z, sc[6]); sc[7] = fmaf(kv, qb.w, sc[7]);
    }
    __syncthreads();
  }

  // reduce 4 wave-partials per (t,h) via Kt overlay
  *(float4*)&Kt[(wid * 64 + lane) * 8    ] = make_float4(sc[0], sc[1], sc[2], sc[3]);
  *(float4*)&Kt[(wid * 64 + lane) * 8 + 4] = make_float4(sc[4], sc[5], sc[6], sc[7]);
  __syncthreads();
  for (int out = tid; out < 512; out += 256) {
    const int t = out >> 3, h = out & 7;
    const float s = (Kt[(0 * 64 + t) * 8 + h] + Kt[(1 * 64 + t) * 8 + h])
                  + (Kt[(2 * 64 + t) * 8 + h] + Kt[(3 * 64 + t) * 8 + h]);
    scores[((size_t)bl * 256 + tq * 64 + t) * 8 + h] = s;
  }
}

// ---------------------------------------------------------------------------
// K3: va_sm_k = softmax (in-block) + VA.  grid (216,3), blk 384.
// r18 structure; t-loop unroll 16 (64B outstanding per thread).
// ---------------------------------------------------------------------------
__global__ __launch_bounds__(384) void va_sm_k(
    const float* __restrict__ V, const float* __restrict__ scores,
    float* __restrict__ VA)
{
  const int bl = blockIdx.x;          // 0..215
  const int dt = blockIdx.y;          // 0..2 (d-third of 384)
  const int tid = threadIdx.x;
  const int d  = dt * 384 + tid;

  __shared__ __align__(16) float at[2048];   // attn[t][h], 8KB
  __shared__ float red[4][8], red2[4][8];

  const int wid = tid >> 6, lane = tid & 63;
  float sc[8], p[8];
  if (tid < 256) {
    const float* src = scores + ((size_t)bl * 256 + tid) * 8;
#pragma unroll
    for (int h = 0; h < 8; h++) sc[h] = src[h];
#pragma unroll
    for (int h = 0; h < 8; h++) {
      float m = sc[h];
#pragma unroll
      for (int o = 1; o < 64; o <<= 1) m = fmaxf(m, __shfl_xor(m, o, 64));
      if (lane == 0) red[wid][h] = m;
    }
  }
  __syncthreads();
  if (tid < 256) {
#pragma unroll
    for (int h = 0; h < 8; h++) {
      const float M = fmaxf(fmaxf(red[0][h], red[1][h]), fmaxf(red[2][h], red[3][h]));
      p[h] = __expf(sc[h] - M);
      float s = p[h];
#pragma unroll
      for (int o = 1; o < 64; o <<= 1) s += __shfl_xor(s, o, 64);
      if (lane == 0) red2[wid][h] = s;
    }
  }
  __syncthreads();
  if (tid < 256) {
#pragma unroll
    for (int h = 0; h < 8; h++) {
      const float S = red2[0][h] + red2[1][h] + red2[2][h] + red2[3][h];
      at[tid * 8 + h] = p[h] * (1.0f / S);
    }
  }
  __syncthreads();

  // VA body: unroll 16 for memory-level parallelism
  const float* Vbase = V + (size_t)bl * 256 * 1152 + d;
  float acc[8] = {0.f, 0.f, 0.f, 0.f, 0.f, 0.f, 0.f, 0.f};
#pragma unroll 16
  for (int t = 0; t < 256; t++) {
    const float v = Vbase[(size_t)t * 1152];
    const float4 a0 = *(const float4*)&at[t * 8];      // broadcast
    const float4 a1 = *(const float4*)&at[t * 8 + 4];  // broadcast
    acc[0] = fmaf(a0.x, v, acc[0]); acc[1] = fmaf(a0.y, v, acc[1]);
    acc[2] = fmaf(a0.z, v, acc[2]); acc[3] = fmaf(a0.w, v, acc[3]);
    acc[4] = fmaf(a1.x, v, acc[4]); acc[5] = fmaf(a1.y, v, acc[5]);
    acc[6] = fmaf(a1.z, v, acc[6]); acc[7] = fmaf(a1.w, v, acc[7]);
  }
  float* dst = VA + (size_t)bl * 8 * 1152 + d;
#pragma unroll
  for (int h = 0; h < 8; h++) dst[(size_t)h * 1152] = acc[h];
}

// ---------------------------------------------------------------------------
// K4: psum[dz][bl][e*8+h] = sum_{d in quarter dz} VA[bl,h,d]*Wv[g,d,h*64+e]
// grid (27,8,4) = (l,h,dz); block 512.
// ---------------------------------------------------------------------------
__global__ __launch_bounds__(512) void pv_mat(
    const float* __restrict__ VA, const float* __restrict__ Wv,
    float* __restrict__ psum)
{
  const int l = blockIdx.x, g = l / 3, h = blockIdx.y, dz = blockIdx.z;
  const int b = threadIdx.x >> 6, lane = threadIdx.x & 63;
  const int bl = b * 27 + l;
  const float* W = Wv + (size_t)g * 1152 * 512 + h * 64 + lane;
  const float* va = VA + ((size_t)bl * 8 + h) * 1152;   // wave-uniform
  const int d0 = dz * 288;
  float a0 = 0.f, a1 = 0.f, a2 = 0.f, a3 = 0.f;
#pragma unroll 2
  for (int d = d0; d < d0 + 288; d += 4) {
    a0 = fmaf(va[d],     W[(size_t)(d)     * 512], a0);
    a1 = fmaf(va[d + 1], W[(size_t)(d + 1) * 512], a1);
    a2 = fmaf(va[d + 2], W[(size_t)(d + 2) * 512], a2);
    a3 = fmaf(va[d + 3], W[(size_t)(d + 3) * 512], a3);
  }
  psum[((size_t)dz * 216 + bl) * 512 + lane * 8 + h] = (a0 + a1) + (a2 + a3);
}

// ---------------------------------------------------------------------------
// K5: out[bl,n] = pooled[bl,:]@Wo[g] + bo[g];  pooled = sum_dz psum + bv_perm
// grid (27,8), block 256.
// ---------------------------------------------------------------------------
__global__ __launch_bounds__(256) void out_gemm(
    const float* __restrict__ psum, const float* __restrict__ bv,
    const float* __restrict__ Wo, const float* __restrict__ bo,
    float* __restrict__ out)
{
  const int l = blockIdx.x, g = l / 3;
  const int n = blockIdx.y * 256 + threadIdx.x;
  __shared__ float pl[8][512];
  for (int i = threadIdx.x; i < 4096; i += 256) {
    const int b = i >> 9, f = i & 511;
    const int bl = b * 27 + l;
    const int e = f >> 3, h = f & 7;           // f = e*8 + h
    float v = bv[g * 512 + h * 64 + e];
#pragma unroll
    for (int dz = 0; dz < 4; dz++)
      v += psum[((size_t)dz * 216 + bl) * 512 + f];
    pl[b][f] = v;
  }
  __syncthreads();
  const float* W = Wo + (size_t)g * 512 * 2048 + n;
  float acc[8] = {0.f, 0.f, 0.f, 0.f, 0.f, 0.f, 0.f, 0.f};
#pragma unroll 4
  for (int f = 0; f < 512; f++) {
    const float w = W[(size_t)f * 2048];
#pragma unroll
    for (int b = 0; b < 8; b++) acc[b] += pl[b][f] * w;
  }
  const float bb = bo[g * 2048 + n];
#pragma unroll
  for (int b = 0; b < 8; b++)
    out[(size_t)(b * 27 + l) * 2048 + n] = acc[b] + bb;
}

// ---------------------------------------------------------------------------
// sentinel: zero-fill f32 output (absmax would read ~1.06e-1 = max|ref|)
// ---------------------------------------------------------------------------
__global__ __launch_bounds__(256) void zfill(float* __restrict__ out, int n) {
  const int i = blockIdx.x * 256 + threadIdx.x;
  if (i < n) out[i] = 0.f;
}

// ---------------------------------------------------------------------------
extern "C" void kernel_launch(void* const* d_in, const int* in_sizes, int n_in,
                              void* d_out, int out_size, void* d_ws, size_t ws_size,
                              hipStream_t stream)
{
  float* out = (float*)d_out;   // f32 output (verified round 4)

  // ---- config guards ----
  bool ok = (n_in == 11) && (out_size == 8 * 27 * 2048);
  if (ok) {
    const int expect[11] = {
      8 * 27 * 256 * 1152,  // K
      8 * 27 * 256 * 1152,  // V
      27 * 1 * 1152,        // query
      9 * 1152 * 512,       // Wq
      9 * 512,              // bq
      9 * 1152 * 512,       // Wk
      9 * 512,              // bk
      9 * 1152 * 512,       // Wv
      9 * 512,              // bv
      9 * 512 * 2048,       // Wo
      9 * 2048              // bo
    };
    for (int i = 0; i < 11; i++) ok = ok && (in_sizes[i] == expect[i]);
  }
  const size_t NEED = 14321664;
  ok = ok && (ws_size >= NEED);

  if (!ok) {
    zfill<<<dim3((out_size + 255) / 256), dim3(256), 0, stream>>>(out, out_size);
    return;
  }

  const float* Kin   = (const float*)d_in[0];
  const float* Vin   = (const float*)d_in[1];
  const float* query = (const float*)d_in[2];
  const float* Wq    = (const float*)d_in[3];
  const float* bq    = (const float*)d_in[4];
  const float* Wk    = (const float*)d_in[5];
  const float* Wv    = (const float*)d_in[7];
  const float* bvp   = (const float*)d_in[8];
  const float* Wo    = (const float*)d_in[9];
  const float* bo    = (const float*)d_in[10];
  // bk (d_in[6]) unused: constant over t, cancels in softmax exactly.

  char* ws = (char*)d_ws;
  float* Qkw     = (float*)(ws + 55296);
  float* scoresw = (float*)(ws + 1050624);
  float* VAw     = (float*)(ws + 4589568);
  float* psumw   = (float*)(ws + 12552192);

  qk_fused<<<dim3(27, 8, 3), dim3(256), 0, stream>>>(query, Wq, bq, Wk, Qkw);
  score_k <<<dim3(216, 4),   dim3(256), 0, stream>>>(Kin, Qkw, scoresw);
  va_sm_k <<<dim3(216, 3),   dim3(384), 0, stream>>>(Vin, scoresw, VAw);
  pv_mat  <<<dim3(27, 8, 4), dim3(512), 0, stream>>>(VAw, Wv, psumw);
  out_gemm<<<dim3(27, 8),    dim3(256), 0, stream>>>(psumw, bvp, Wo, bo, out);
}

// Round 23
// 262.939 us; speedup vs baseline: 1.3077x; 1.0032x over previous
//
#include <hip/hip_runtime.h>
#include <stdint.h>

// ---- dims ----
// B=8, L=27, T=256, D=1152, GS=3, G=9, DD=512, H=8, HD=64, NQ=1, OD=2048
// Output dtype: FLOAT32 (verified round 4).
//
// Round 23: r19/r22 base (best: 262-264us) + ONE change: va_sm_k loads V
// as float2 (512B/wave-instr vs 256B; G13). Block 384 = 2 token-groups x
// 192 f2-slots; halves combined via LDS. All else byte-identical to r22.
// Algebra (verified r9-r22): scores = K·Qk (bk cancels in softmax);
// pooled = (attn·V)·Wv + bv. All f32.

// ---------------------------------------------------------------------------
// K1: qk_fused. grid (27,8,3) = (l,h,dc), block 256.  [verbatim r22]
// ---------------------------------------------------------------------------
__global__ __launch_bounds__(256) void qk_fused(
    const float* __restrict__ query, const float* __restrict__ Wq,
    const float* __restrict__ bq, const float* __restrict__ Wk,
    float* __restrict__ Qk)
{
  const int l = blockIdx.x, g = l / 3;
  const int h = blockIdx.y;
  const int dc = blockIdx.z;          // 0..2 (384 d each)
  const int tid = threadIdx.x;

  __shared__ float qv[1152];
  __shared__ float part[4][64];
  __shared__ float Qps[64];

  for (int i = tid; i < 1152; i += 256) qv[i] = query[(size_t)l * 1152 + i];
  __syncthreads();

  {
    const int e = tid & 63;
    const int kq = tid >> 6;          // 0..3, 288 d' each
    const float* W = Wq + (size_t)g * 1152 * 512 + h * 64 + e;
    float a0 = 0.f, a1 = 0.f;
    const int d0 = kq * 288;
#pragma unroll 4
    for (int d = d0; d < d0 + 288; d += 2) {
      a0 += qv[d]     * W[(size_t)d * 512];
      a1 += qv[d + 1] * W[(size_t)(d + 1) * 512];
    }
    part[kq][e] = a0 + a1;
  }
  __syncthreads();
  if (tid < 64) {
    const float r = part[0][tid] + part[1][tid] + part[2][tid] + part[3][tid];
    Qps[tid] = (r + bq[g * 512 + h * 64 + tid]) * 0.125f;
  }
  __syncthreads();

  const float4* q4base = (const float4*)Qps;
#pragma unroll
  for (int it = 0; it < 6; it++) {
    const int slot = it * 256 + tid;  // 0..1535
    const int eg = slot & 3;
    const int d  = dc * 384 + (slot >> 2);
    const float4* q4 = q4base + eg * 4;
    const float4* w4 = (const float4*)(Wk + (size_t)g * 1152 * 512 + (size_t)d * 512 + h * 64 + eg * 16);
    float acc = 0.f;
#pragma unroll
    for (int e = 0; e < 4; e++) {
      const float4 a = q4[e], b = w4[e];
      acc += a.x * b.x + a.y * b.y + a.z * b.z + a.w * b.w;
    }
    acc += __shfl_xor(acc, 1, 64);
    acc += __shfl_xor(acc, 2, 64);
    if (eg == 0) Qk[((size_t)l * 1152 + d) * 8 + h] = acc;
  }
}

// ---------------------------------------------------------------------------
// K2: scores[bl][t][h] = sum_d K[bl,t,d] * Qk[l,d,h]   [verbatim r22]
// grid (216,4 token-tiles), block 256 (4 waves). lane = token, wave = d-slice.
// ---------------------------------------------------------------------------
__global__ __launch_bounds__(256) void score_k(
    const float* __restrict__ K, const float* __restrict__ Qk,
    float* __restrict__ scores)
{
  const int bl = blockIdx.x;          // 0..215
  const int tq = blockIdx.y;          // 0..3 (64-token tile)
  const int l = bl % 27;
  const int tid = threadIdx.x;
  const int lane = tid & 63;          // token within tile
  const int wid = tid >> 6;           // wave = d-slice (24 d of each 96)

  __shared__ __align__(16) float Kt[96 * 65];   // 24,960 B; reused for reduce
  __shared__ __align__(16) float Qs[96 * 8];    // 3,072 B

  const float* Kbase = K + ((size_t)bl * 256 + tq * 64) * 1152;
  const float* Qbase = Qk + (size_t)l * 1152 * 8;

  float4 kreg[6];
  float4 qreg;

  auto loadChunk = [&](int dc) {
#pragma unroll
    for (int it = 0; it < 6; it++) {
      const int flat = it * 256 + tid;       // float4 slot
      const int row = flat / 24;             // token
      const int col = flat % 24;             // d4-slot
      kreg[it] = *(const float4*)(Kbase + (size_t)row * 1152 + dc * 96 + col * 4);
    }
    if (tid < 192)
      qreg = ((const float4*)(Qbase + (size_t)dc * 96 * 8))[tid];
  };
  auto storeChunk = [&]() {
#pragma unroll
    for (int it = 0; it < 6; it++) {
      const int flat = it * 256 + tid;
      const int row = flat / 24;
      const int col = flat % 24;
      Kt[(col * 4 + 0) * 65 + row] = kreg[it].x;
      Kt[(col * 4 + 1) * 65 + row] = kreg[it].y;
      Kt[(col * 4 + 2) * 65 + row] = kreg[it].z;
      Kt[(col * 4 + 3) * 65 + row] = kreg[it].w;
    }
    if (tid < 192)
      ((float4*)Qs)[tid] = qreg;
  };

  float sc[8] = {0.f, 0.f, 0.f, 0.f, 0.f, 0.f, 0.f, 0.f};

  loadChunk(0);
  for (int dc = 0; dc < 12; dc++) {
    storeChunk();
    __syncthreads();
    if (dc + 1 < 12) loadChunk(dc + 1);   // loads fly over compute
    // compute: wave wid handles d in [wid*24, wid*24+24)
#pragma unroll 4
    for (int j = 0; j < 24; j++) {
      const int d = wid * 24 + j;
      const float kv = Kt[d * 65 + lane];            // bank=(d+lane)%32: free
      const float4 qa = *(const float4*)&Qs[d * 8];  // wave-uniform broadcast
      const float4 qb = *(const float4*)&Qs[d * 8 + 4];
      sc[0] = fmaf(kv, qa.x, sc[0]); sc[1] = fmaf(kv, qa.y, sc[1]);
      sc[2] = fmaf(kv, qa.z, sc[2]); sc[3] = fmaf(kv, qa.w, sc[3]);
      sc[4] = fmaf(kv, qb.x, sc[4]); sc[5] = fmaf(kv, qb.y, sc[5]);
      sc[6] = fmaf(kv, qb.z, sc[6]); sc[7] = fmaf(kv, qb.w, sc[7]);
    }
    __syncthreads();
  }

  // reduce 4 wave-partials per (t,h) via Kt overlay
  *(float4*)&Kt[(wid * 64 + lane) * 8    ] = make_float4(sc[0], sc[1], sc[2], sc[3]);
  *(float4*)&Kt[(wid * 64 + lane) * 8 + 4] = make_float4(sc[4], sc[5], sc[6], sc[7]);
  __syncthreads();
  for (int out = tid; out < 512; out += 256) {
    const int t = out >> 3, h = out & 7;
    const float s = (Kt[(0 * 64 + t) * 8 + h] + Kt[(1 * 64 + t) * 8 + h])
                  + (Kt[(2 * 64 + t) * 8 + h] + Kt[(3 * 64 + t) * 8 + h]);
    scores[((size_t)bl * 256 + tq * 64 + t) * 8 + h] = s;
  }
}

// ---------------------------------------------------------------------------
// K3: va_sm_k = softmax (in-block) + VA.  grid (216,3), blk 384.
// CHANGE (r23): V loads widened to float2. Block = 2 token-groups x 192
// f2-slots; tg0 covers t 0..127, tg1 covers 128..255; halves combined via
// LDS comb[]. Softmax section verbatim r22.
// ---------------------------------------------------------------------------
__global__ __launch_bounds__(384) void va_sm_k(
    const float* __restrict__ V, const float* __restrict__ scores,
    float* __restrict__ VA)
{
  const int bl = blockIdx.x;          // 0..215
  const int dt = blockIdx.y;          // 0..2 (d-third of 384)
  const int tid = threadIdx.x;

  __shared__ __align__(16) float at[2048];     // attn[t][h], 8KB
  __shared__ __align__(16) float2 comb[192][8];// 12KB combine buffer
  __shared__ float red[4][8], red2[4][8];

  const int wid = tid >> 6, lane = tid & 63;
  float sc[8], p[8];
  if (tid < 256) {
    const float* src = scores + ((size_t)bl * 256 + tid) * 8;
#pragma unroll
    for (int h = 0; h < 8; h++) sc[h] = src[h];
#pragma unroll
    for (int h = 0; h < 8; h++) {
      float m = sc[h];
#pragma unroll
      for (int o = 1; o < 64; o <<= 1) m = fmaxf(m, __shfl_xor(m, o, 64));
      if (lane == 0) red[wid][h] = m;
    }
  }
  __syncthreads();
  if (tid < 256) {
#pragma unroll
    for (int h = 0; h < 8; h++) {
      const float M = fmaxf(fmaxf(red[0][h], red[1][h]), fmaxf(red[2][h], red[3][h]));
      p[h] = __expf(sc[h] - M);
      float s = p[h];
#pragma unroll
      for (int o = 1; o < 64; o <<= 1) s += __shfl_xor(s, o, 64);
      if (lane == 0) red2[wid][h] = s;
    }
  }
  __syncthreads();
  if (tid < 256) {
#pragma unroll
    for (int h = 0; h < 8; h++) {
      const float S = red2[0][h] + red2[1][h] + red2[2][h] + red2[3][h];
      at[tid * 8 + h] = p[h] * (1.0f / S);
    }
  }
  __syncthreads();

  // VA body: float2 lanes; thread (tg, ds): tg = t-half, ds = f2-slot.
  const int ds = tid % 192;           // 0..191 (waves don't straddle: 192=3 waves)
  const int tg = tid / 192;           // 0..1
  const int d  = dt * 384 + ds * 2;
  const float* Vbase = V + ((size_t)bl * 256 + tg * 128) * 1152 + d;

  float2 acc[8];
#pragma unroll
  for (int h = 0; h < 8; h++) acc[h] = make_float2(0.f, 0.f);

#pragma unroll 16
  for (int t = 0; t < 128; t++) {
    const float2 v = *(const float2*)(Vbase + (size_t)t * 1152);
    const int ta = tg * 128 + t;
    const float4 a0 = *(const float4*)&at[ta * 8];      // broadcast
    const float4 a1 = *(const float4*)&at[ta * 8 + 4];  // broadcast
    acc[0].x = fmaf(a0.x, v.x, acc[0].x); acc[0].y = fmaf(a0.x, v.y, acc[0].y);
    acc[1].x = fmaf(a0.y, v.x, acc[1].x); acc[1].y = fmaf(a0.y, v.y, acc[1].y);
    acc[2].x = fmaf(a0.z, v.x, acc[2].x); acc[2].y = fmaf(a0.z, v.y, acc[2].y);
    acc[3].x = fmaf(a0.w, v.x, acc[3].x); acc[3].y = fmaf(a0.w, v.y, acc[3].y);
    acc[4].x = fmaf(a1.x, v.x, acc[4].x); acc[4].y = fmaf(a1.x, v.y, acc[4].y);
    acc[5].x = fmaf(a1.y, v.x, acc[5].x); acc[5].y = fmaf(a1.y, v.y, acc[5].y);
    acc[6].x = fmaf(a1.z, v.x, acc[6].x); acc[6].y = fmaf(a1.z, v.y, acc[6].y);
    acc[7].x = fmaf(a1.w, v.x, acc[7].x); acc[7].y = fmaf(a1.w, v.y, acc[7].y);
  }

  // combine the two t-halves via LDS; tg1 publishes, tg0 adds + writes.
  if (tg == 1) {
#pragma unroll
    for (int h = 0; h < 8; h++) comb[ds][h] = acc[h];
  }
  __syncthreads();
  if (tg == 0) {
    float* dst = VA + (size_t)bl * 8 * 1152 + d;
#pragma unroll
    for (int h = 0; h < 8; h++) {
      const float2 o = comb[ds][h];
      float2 r; r.x = acc[h].x + o.x; r.y = acc[h].y + o.y;
      *(float2*)(dst + (size_t)h * 1152) = r;
    }
  }
}

// ---------------------------------------------------------------------------
// K4: psum[dz][bl][e*8+h] = sum_{d in quarter dz} VA[bl,h,d]*Wv[g,d,h*64+e]
// grid (27,8,4) = (l,h,dz); block 512.  [verbatim r22]
// ---------------------------------------------------------------------------
__global__ __launch_bounds__(512) void pv_mat(
    const float* __restrict__ VA, const float* __restrict__ Wv,
    float* __restrict__ psum)
{
  const int l = blockIdx.x, g = l / 3, h = blockIdx.y, dz = blockIdx.z;
  const int b = threadIdx.x >> 6, lane = threadIdx.x & 63;
  const int bl = b * 27 + l;
  const float* W = Wv + (size_t)g * 1152 * 512 + h * 64 + lane;
  const float* va = VA + ((size_t)bl * 8 + h) * 1152;   // wave-uniform
  const int d0 = dz * 288;
  float a0 = 0.f, a1 = 0.f, a2 = 0.f, a3 = 0.f;
#pragma unroll 2
  for (int d = d0; d < d0 + 288; d += 4) {
    a0 = fmaf(va[d],     W[(size_t)(d)     * 512], a0);
    a1 = fmaf(va[d + 1], W[(size_t)(d + 1) * 512], a1);
    a2 = fmaf(va[d + 2], W[(size_t)(d + 2) * 512], a2);
    a3 = fmaf(va[d + 3], W[(size_t)(d + 3) * 512], a3);
  }
  psum[((size_t)dz * 216 + bl) * 512 + lane * 8 + h] = (a0 + a1) + (a2 + a3);
}

// ---------------------------------------------------------------------------
// K5: out[bl,n] = pooled[bl,:]@Wo[g] + bo[g];  pooled = sum_dz psum + bv_perm
// grid (27,8), block 256.  [verbatim r22]
// ---------------------------------------------------------------------------
__global__ __launch_bounds__(256) void out_gemm(
    const float* __restrict__ psum, const float* __restrict__ bv,
    const float* __restrict__ Wo, const float* __restrict__ bo,
    float* __restrict__ out)
{
  const int l = blockIdx.x, g = l / 3;
  const int n = blockIdx.y * 256 + threadIdx.x;
  __shared__ float pl[8][512];
  for (int i = threadIdx.x; i < 4096; i += 256) {
    const int b = i >> 9, f = i & 511;
    const int bl = b * 27 + l;
    const int e = f >> 3, h = f & 7;           // f = e*8 + h
    float v = bv[g * 512 + h * 64 + e];
#pragma unroll
    for (int dz = 0; dz < 4; dz++)
      v += psum[((size_t)dz * 216 + bl) * 512 + f];
    pl[b][f] = v;
  }
  __syncthreads();
  const float* W = Wo + (size_t)g * 512 * 2048 + n;
  float acc[8] = {0.f, 0.f, 0.f, 0.f, 0.f, 0.f, 0.f, 0.f};
#pragma unroll 4
  for (int f = 0; f < 512; f++) {
    const float w = W[(size_t)f * 2048];
#pragma unroll
    for (int b = 0; b < 8; b++) acc[b] += pl[b][f] * w;
  }
  const float bb = bo[g * 2048 + n];
#pragma unroll
  for (int b = 0; b < 8; b++)
    out[(size_t)(b * 27 + l) * 2048 + n] = acc[b] + bb;
}

// ---------------------------------------------------------------------------
// sentinel: zero-fill f32 output (absmax would read ~1.06e-1 = max|ref|)
// ---------------------------------------------------------------------------
__global__ __launch_bounds__(256) void zfill(float* __restrict__ out, int n) {
  const int i = blockIdx.x * 256 + threadIdx.x;
  if (i < n) out[i] = 0.f;
}

// ---------------------------------------------------------------------------
extern "C" void kernel_launch(void* const* d_in, const int* in_sizes, int n_in,
                              void* d_out, int out_size, void* d_ws, size_t ws_size,
                              hipStream_t stream)
{
  float* out = (float*)d_out;   // f32 output (verified round 4)

  // ---- config guards ----
  bool ok = (n_in == 11) && (out_size == 8 * 27 * 2048);
  if (ok) {
    const int expect[11] = {
      8 * 27 * 256 * 1152,  // K
      8 * 27 * 256 * 1152,  // V
      27 * 1 * 1152,        // query
      9 * 1152 * 512,       // Wq
      9 * 512,              // bq
      9 * 1152 * 512,       // Wk
      9 * 512,              // bk
      9 * 1152 * 512,       // Wv
      9 * 512,              // bv
      9 * 512 * 2048,       // Wo
      9 * 2048              // bo
    };
    for (int i = 0; i < 11; i++) ok = ok && (in_sizes[i] == expect[i]);
  }
  const size_t NEED = 14321664;
  ok = ok && (ws_size >= NEED);

  if (!ok) {
    zfill<<<dim3((out_size + 255) / 256), dim3(256), 0, stream>>>(out, out_size);
    return;
  }

  const float* Kin   = (const float*)d_in[0];
  const float* Vin   = (const float*)d_in[1];
  const float* query = (const float*)d_in[2];
  const float* Wq    = (const float*)d_in[3];
  const float* bq    = (const float*)d_in[4];
  const float* Wk    = (const float*)d_in[5];
  const float* Wv    = (const float*)d_in[7];
  const float* bvp   = (const float*)d_in[8];
  const float* Wo    = (const float*)d_in[9];
  const float* bo    = (const float*)d_in[10];
  // bk (d_in[6]) unused: constant over t, cancels in softmax exactly.

  char* ws = (char*)d_ws;
  float* Qkw     = (float*)(ws + 55296);
  float* scoresw = (float*)(ws + 1050624);
  float* VAw     = (float*)(ws + 4589568);
  float* psumw   = (float*)(ws + 12552192);

  qk_fused<<<dim3(27, 8, 3), dim3(256), 0, stream>>>(query, Wq, bq, Wk, Qkw);
  score_k <<<dim3(216, 4),   dim3(256), 0, stream>>>(Kin, Qkw, scoresw);
  va_sm_k <<<dim3(216, 3),   dim3(384), 0, stream>>>(Vin, scoresw, VAw);
  pv_mat  <<<dim3(27, 8, 4), dim3(512), 0, stream>>>(VAw, Wv, psumw);
  out_gemm<<<dim3(27, 8),    dim3(256), 0, stream>>>(psumw, bvp, Wo, bo, out);
}